// Round 2
// baseline (89.448 us; speedup 1.0000x reference)
//
#include <hip/hip_runtime.h>
#include <math.h>

// Problem constants (fixed by reference): D=H=W=40, VEC_DIM=32, RANK=2
constexpr int DV = 40;     // volume dim per axis
constexpr int NP = 39;     // pooled dim per axis (VALID, r=2, stride 1)
constexpr int VD = 32;     // vector dim m
constexpr float TWO_PI = 6.28318530717958647692f;

// One block per (k1,k2). Register-resident M-row (phase 1) and R/omega rows
// (phase 2) so the only LDS traffic is broadcast b128 reads + strided b32
// writes. R2: kills the 2-LDS-ops-per-term pattern that made R1 LDS-bound.
__global__ __launch_bounds__(256) void ndk_kernel(
    const float* __restrict__ vol,   // [40][40][40][32]
    const float* __restrict__ Mw,    // [32][32]  (x = v M^T)
    const float* __restrict__ P,     // [32][32]
    float* __restrict__ out)         // [39*39*39][32]
{
    __shared__ alignas(16) float pool[8 * VD];   // pool[s][c]
    __shared__ alignas(16) float xs[NP * VD];    // xs[k3][j]

    const int tid  = threadIdx.x;
    const int lane = tid & 31;     // c (phase1 pool) / j (phase1 x) / i (phase2)
    const int sub  = tid >> 5;     // 8 subgroups -> k3 = t*8 + sub
    const int bx = blockIdx.x;
    const int k1 = bx / NP, k2 = bx % NP;
    const float k1f = (float)k1, k2f = (float)k2;

    // ---- M row into registers: Mr[c] = Mw[lane][c] (lane = output j) ----
    float Mr[VD];
    {
        const float4* Mrow = (const float4*)(Mw + lane * VD);   // 128B-aligned rows
        #pragma unroll
        for (int c4 = 0; c4 < 8; ++c4) {
            float4 m = Mrow[c4];
            Mr[4*c4+0] = m.x; Mr[4*c4+1] = m.y; Mr[4*c4+2] = m.z; Mr[4*c4+3] = m.w;
        }
    }

    // ---- phase 1: pool (lane=c) then x = pooled . M^T (lane=j) ----
    const float4* poolv = (const float4*)pool;
    #pragma unroll
    for (int t = 0; t < 5; ++t) {
        const int k3 = t * 8 + sub;
        float pv = 0.f;
        if (k3 < NP) {
            const float* vp = vol + ((size_t)(k1 * DV + k2) * DV + k3) * VD + lane;
            constexpr int SW = VD, SH = DV * VD, SD = DV * DV * VD;
            pv = vp[0]       + vp[SW]
               + vp[SH]      + vp[SH + SW]
               + vp[SD]      + vp[SD + SW]
               + vp[SD + SH] + vp[SD + SH + SW];
            pv *= 0.125f;
        }
        __syncthreads();                 // previous chunk's readers done
        pool[sub * VD + lane] = pv;      // b32, conflict-free (bank = lane)
        __syncthreads();
        if (k3 < NP) {
            float x = 0.f;
            #pragma unroll
            for (int c4 = 0; c4 < 8; ++c4) {
                float4 p4 = poolv[sub * 8 + c4];   // b128 broadcast (uniform/half-wave)
                x += p4.x * Mr[4*c4+0] + p4.y * Mr[4*c4+1]
                   + p4.z * Mr[4*c4+2] + p4.w * Mr[4*c4+3];
            }
            xs[k3 * VD + lane] = x;      // b32, conflict-free
        }
    }
    __syncthreads();

    // ---- build R/omega rows in registers (lane = i); Mr is dead now ----
    float rx[VD], wv[VD];
    {
        const float4* Prow = (const float4*)(P + lane * VD);
        #pragma unroll
        for (int j4 = 0; j4 < 8; ++j4) {
            float4 p4 = Prow[j4];
            float pj[4] = { p4.x, p4.y, p4.z, p4.w };
            #pragma unroll
            for (int u = 0; u < 4; ++u) {
                const int j = 4 * j4 + u;
                const float w = TWO_PI / (float)(lane * VD + j + 2);
                wv[j] = w;
                rx[j] = pj[u] * __cosf(k1f * w) * __cosf(k2f * w);
            }
        }
    }

    // ---- phase 2: Nk[b(k3), i] = sum_j xs[k3][j] * rx[j] * cos(k3*wv[j]) ----
    const float4* xsv = (const float4*)xs;
    const long obase = (long)bx * NP;
    #pragma unroll
    for (int t = 0; t < 5; ++t) {
        const int k3 = t * 8 + sub;
        if (k3 < NP) {
            const float k3f = (float)k3;
            float acc = 0.f;
            #pragma unroll
            for (int j4 = 0; j4 < 8; ++j4) {
                float4 xv = xsv[k3 * 8 + j4];      // b128 broadcast (uniform/half-wave)
                acc += xv.x * rx[4*j4+0] * __cosf(k3f * wv[4*j4+0]);
                acc += xv.y * rx[4*j4+1] * __cosf(k3f * wv[4*j4+1]);
                acc += xv.z * rx[4*j4+2] * __cosf(k3f * wv[4*j4+2]);
                acc += xv.w * rx[4*j4+3] * __cosf(k3f * wv[4*j4+3]);
            }
            out[(obase + k3) * VD + lane] = acc;   // coalesced
        }
    }
}

extern "C" void kernel_launch(void* const* d_in, const int* in_sizes, int n_in,
                              void* d_out, int out_size, void* d_ws, size_t ws_size,
                              hipStream_t stream) {
    const float* vol = (const float*)d_in[0];
    const float* Mw  = (const float*)d_in[1];
    const float* P   = (const float*)d_in[2];
    float* out = (float*)d_out;
    (void)in_sizes; (void)n_in; (void)out_size; (void)d_ws; (void)ws_size;

    dim3 grid(NP * NP);   // 1521 blocks, one per (k1,k2)
    dim3 block(256);
    ndk_kernel<<<grid, block, 0, stream>>>(vol, Mw, P, out);
}

// Round 3
// 89.341 us; speedup vs baseline: 1.0012x; 1.0012x over previous
//
#include <hip/hip_runtime.h>
#include <math.h>

// D=H=W=40, m=32, rank=2 -> pooled grid 39^3, B = 1521 rows x 39 k3
constexpr int DV = 40;
constexpr int NP = 39;
constexpr int VD = 32;
constexpr int NROWS = NP * NP;   // 1521 (k1,k2) rows
constexpr float TWO_PI = 6.28318530717958647692f;

// fp32 -> bf16 round-to-nearest-even
__device__ __forceinline__ unsigned short f2bf(float f) {
    unsigned u = __float_as_uint(f);
    u = (u + 0x7fffu + ((u >> 16) & 1u)) >> 16;
    return (unsigned short)u;
}
__device__ __forceinline__ float bflo(unsigned u) { return __uint_as_float(u << 16); }
__device__ __forceinline__ float bfhi(unsigned u) { return __uint_as_float(u & 0xffff0000u); }

// Block = 256 threads = 4 waves = 2 (k1,k2) rows; wave covers 32 i x 2 k3-strips.
// Hot loop: d_{k+1} = a*d_k - d_{k-1} (a = 2cos w) replaces cos -> zero trans
// ops per term. x and pooled staged in LDS as bf16 (halves LDS return-bus).
__global__ __launch_bounds__(256, 3) void ndk_kernel(
    const float* __restrict__ vol,   // [40][40][40][32]
    const float* __restrict__ Mw,    // [32][32] (x = v M^T)
    const float* __restrict__ P,     // [32][32]
    float* __restrict__ out)         // [1521*39][32]
{
    __shared__ __align__(16) unsigned short pool_bf[2][NP][VD]; // 4992 B
    __shared__ __align__(16) unsigned short xs_bf[2][NP][VD];   // 4992 B

    const int tid  = threadIdx.x;
    const int lane = tid & 31;
    const int bx   = blockIdx.x;

    // ---- phase A: 2x2x2 mean-pool -> bf16 LDS (slot = row,k3,c; c = lane) ----
    for (int s = tid; s < 2 * NP * VD; s += 256) {
        int row = 0, s2 = s;
        if (s2 >= NP * VD) { row = 1; s2 -= NP * VD; }
        const int k3 = s2 >> 5, c = s2 & 31;
        const int g  = 2 * bx + row;
        float pv = 0.f;
        if (g < NROWS) {
            const int k1 = g / NP, k2 = g - (g / NP) * NP;
            const float* vp = vol + ((size_t)(k1 * DV + k2) * DV + k3) * VD + c;
            constexpr int SW = VD, SH = DV * VD, SD = DV * DV * VD;
            pv = vp[0]       + vp[SW]
               + vp[SH]      + vp[SH + SW]
               + vp[SD]      + vp[SD + SW]
               + vp[SD + SH] + vp[SD + SH + SW];
            pv *= 0.125f;
        }
        pool_bf[row][k3][c] = f2bf(pv);
    }

    // M row into regs (lane = output j) while phase A drains
    float Mr[VD];
    {
        const float4* m4 = (const float4*)(Mw + lane * VD);
        #pragma unroll
        for (int c4 = 0; c4 < 8; ++c4) {
            float4 m = m4[c4];
            Mr[4*c4] = m.x; Mr[4*c4+1] = m.y; Mr[4*c4+2] = m.z; Mr[4*c4+3] = m.w;
        }
    }
    __syncthreads();

    // ---- phase B: x[k3][j] = pooled[k3] . M[j] -> bf16 LDS (j = lane) ----
    for (int s = tid; s < 2 * NP * VD; s += 256) {
        int row = 0, s2 = s;
        if (s2 >= NP * VD) { row = 1; s2 -= NP * VD; }
        const int k3 = s2 >> 5;                       // (s2&31) == lane
        const uint4* pw = (const uint4*)&pool_bf[row][k3][0]; // 4x b128 broadcast
        float x = 0.f;
        #pragma unroll
        for (int r = 0; r < 4; ++r) {
            uint4 qv = pw[r];
            const int c = r * 8;
            x += bflo(qv.x)*Mr[c]   + bfhi(qv.x)*Mr[c+1]
               + bflo(qv.y)*Mr[c+2] + bfhi(qv.y)*Mr[c+3]
               + bflo(qv.z)*Mr[c+4] + bfhi(qv.z)*Mr[c+5]
               + bflo(qv.w)*Mr[c+6] + bfhi(qv.w)*Mr[c+7];
        }
        xs_bf[row][k3][lane] = f2bf(x);               // b16, 2-way = free
    }
    __syncthreads();

    // ---- phase C: per-thread recurrence state for (i = lane, all 32 j) ----
    const int wv  = tid >> 6;          // wave 0..3
    const int row = wv >> 1;           // 2 waves per row
    const int kh  = (tid >> 5) & 1;    // half-wave -> k3 strip
    const int q   = (wv & 1) * 2 + kh; // strip 0..3
    const int i   = lane;
    const int g   = 2 * bx + row;
    const bool valid = g < NROWS;
    const int kstart = q * 10;
    const int kend   = min(kstart + 10, NP);   // {10,20,30,39}
    const float k1f = (float)(g / NP);
    const float k2f = (float)(g - (g / NP) * NP);

    float av[VD], d0[VD], dm1[VD];     // a = 2cos w; d_k = rx*cos(k w)
    {
        const float4* p4 = (const float4*)(P + i * VD);
        #pragma unroll
        for (int j4 = 0; j4 < 8; ++j4) {
            float4 pr = p4[j4];
            float pj[4] = { pr.x, pr.y, pr.z, pr.w };
            #pragma unroll
            for (int u = 0; u < 4; ++u) {
                const int j = j4 * 4 + u;
                const float w  = __fdividef(TWO_PI, (float)(i * VD + j + 2));
                const float rx = pj[u] * __cosf(k1f * w) * __cosf(k2f * w);
                av[j]  = 2.f * __cosf(w);
                d0[j]  = rx * __cosf((float)kstart * w);
                dm1[j] = rx * __cosf((float)(kstart - 1) * w);  // cos even: k=-1 ok
            }
        }
    }

    // ---- phase D: per k3: acc = sum_j x*d0[j]; advance recurrence ----
    for (int t = 0; t < 10; ++t) {
        const int k3  = kstart + t;
        const int k3r = min(k3, NP - 1);               // clamp OOB read (q3,t=9)
        const uint4* xw = (const uint4*)&xs_bf[row][k3r][0]; // 4x b128 broadcast
        float acc = 0.f;
        #pragma unroll
        for (int r = 0; r < 4; ++r) {
            uint4 qv = xw[r];
            const int j = r * 8;
            acc += bflo(qv.x)*d0[j]   + bfhi(qv.x)*d0[j+1]
                 + bflo(qv.y)*d0[j+2] + bfhi(qv.y)*d0[j+3]
                 + bflo(qv.z)*d0[j+4] + bfhi(qv.z)*d0[j+5]
                 + bflo(qv.w)*d0[j+6] + bfhi(qv.w)*d0[j+7];
        }
        #pragma unroll
        for (int j = 0; j < VD; ++j) {
            const float dn = __builtin_fmaf(av[j], d0[j], -dm1[j]);
            dm1[j] = d0[j];
            d0[j]  = dn;
        }
        if (valid && k3 < kend)
            out[((size_t)g * NP + k3) * VD + i] = acc;  // coalesced 128B/half-wave
    }
}

extern "C" void kernel_launch(void* const* d_in, const int* in_sizes, int n_in,
                              void* d_out, int out_size, void* d_ws, size_t ws_size,
                              hipStream_t stream) {
    const float* vol = (const float*)d_in[0];
    const float* Mw  = (const float*)d_in[1];
    const float* P   = (const float*)d_in[2];
    float* out = (float*)d_out;
    (void)in_sizes; (void)n_in; (void)out_size; (void)d_ws; (void)ws_size;

    dim3 grid((NROWS + 1) / 2);   // 761 blocks, 2 rows each
    dim3 block(256);
    ndk_kernel<<<grid, block, 0, stream>>>(vol, Mw, P, out);
}